// Round 1
// baseline (732.577 us; speedup 1.0000x reference)
//
#include <hip/hip_runtime.h>
#include <math.h>

#define B_  32
#define L_  4096
#define H_  512
#define V_  32000

typedef __attribute__((ext_vector_type(4))) float f32x4;
typedef __attribute__((ext_vector_type(2))) float f32x2;
typedef __attribute__((ext_vector_type(8))) short short8;
typedef __attribute__((ext_vector_type(4))) unsigned short u16x4;

__device__ __forceinline__ unsigned short bf16_rne(float x){
  union { float f; unsigned int u; } v; v.f = x;
  unsigned int u = v.u;
  return (unsigned short)((u + 0x7FFFu + ((u >> 16) & 1u)) >> 16);
}
__device__ __forceinline__ float bf16_f32(unsigned short h){
  union { unsigned int u; float f; } v; v.u = ((unsigned int)h) << 16;
  return v.f;
}

// ---------------- W2 -> bf16 hi/lo split (1 MB, done per call) ----------------
__global__ __launch_bounds__(256) void k_convert_w2(
    const float* __restrict__ w2, unsigned short* __restrict__ hi,
    unsigned short* __restrict__ lo){
  int i = (blockIdx.x * 256 + threadIdx.x) * 4;  // 262144 elems total
  f32x4 v = *(const f32x4*)(w2 + i);
  u16x4 h, l;
  #pragma unroll
  for (int e = 0; e < 4; ++e) {
    unsigned short hb = bf16_rne(v[e]);
    h[e] = hb;
    l[e] = bf16_rne(v[e] - bf16_f32(hb));
  }
  *(u16x4*)(hi + i) = h;
  *(u16x4*)(lo + i) = l;
}

// ---------------- gates = x@Wih^T + b_ih + h0@Whh^T + b_hh ----------------
__global__ __launch_bounds__(256) void k_gates(
    const float* __restrict__ x, const float* __restrict__ h0,
    const float* __restrict__ Wih, const float* __restrict__ Whh,
    const float* __restrict__ bih, const float* __restrict__ bhh,
    float* __restrict__ gates){
  __shared__ float sx[H_], sh[H_];
  int b = blockIdx.y, t = threadIdx.x;
  sx[t] = x[b*H_ + t]; sx[t+256] = x[b*H_ + t + 256];
  sh[t] = h0[b*H_ + t]; sh[t+256] = h0[b*H_ + t + 256];
  __syncthreads();
  int j = blockIdx.x * 256 + t;
  const float* wi = Wih + j*H_;
  const float* wh = Whh + j*H_;
  float acc = bih[j] + bhh[j];
  #pragma unroll 4
  for (int k = 0; k < H_; k += 4) {
    f32x4 a = *(const f32x4*)(wi + k);
    f32x4 c = *(const f32x4*)(wh + k);
    acc += a[0]*sx[k] + a[1]*sx[k+1] + a[2]*sx[k+2] + a[3]*sx[k+3];
    acc += c[0]*sh[k] + c[1]*sh[k+1] + c[2]*sh[k+2] + c[3]*sh[k+3];
  }
  gates[b*2048 + j] = acc;
}

// ---------------- LSTM cell elementwise ----------------
__global__ __launch_bounds__(256) void k_lstm(
    const float* __restrict__ gates, const float* __restrict__ c0,
    float* __restrict__ out_h, float* __restrict__ out_c, float* __restrict__ cc){
  int idx = blockIdx.x * 256 + threadIdx.x;   // 16384
  int b = idx >> 9, hh = idx & 511;
  const float* g = gates + b*2048;
  float gi = g[hh], gf = g[512+hh], gg = g[1024+hh], go = g[1536+hh];
  float si = 1.f/(1.f+expf(-gi));
  float sf = 1.f/(1.f+expf(-gf));
  float so = 1.f/(1.f+expf(-go));
  float c = sf * c0[idx] + si * tanhf(gg);
  float h = so * tanhf(c);
  out_h[idx] = h; out_c[idx] = c;
  cc[b*1024 + hh] = h;   // first half of combined_context
}

// ---------------- q = h@W1^T + b1 ----------------
__global__ __launch_bounds__(256) void k_q(
    const float* __restrict__ cc, const float* __restrict__ W1,
    const float* __restrict__ b1, float* __restrict__ q){
  __shared__ float shh[H_];
  int b = blockIdx.y, t = threadIdx.x;
  shh[t] = cc[b*1024 + t]; shh[t+256] = cc[b*1024 + t + 256];
  __syncthreads();
  int j = blockIdx.x*256 + t;
  const float* w = W1 + j*H_;
  float acc = b1[j];
  #pragma unroll 4
  for (int k = 0; k < H_; k += 4){
    f32x4 a = *(const f32x4*)(w + k);
    acc += a[0]*shh[k] + a[1]*shh[k+1] + a[2]*shh[k+2] + a[3]*shh[k+3];
  }
  q[b*H_ + j] = acc;
}

// ---------------- scores: split-bf16 MFMA GEMM + tanh + u1-dot + mask ----------
// WG: 512 thr (8 waves), 32 doc rows, full K=512 in LDS (hi/lo, XOR-swizzled),
// full N=512 as 8 waves x 4 j-tiles. 3-term MFMA: hh + lh + hl.
__global__ __launch_bounds__(512, 4) void k_scores(
    const float* __restrict__ doc, const unsigned short* __restrict__ w2hi,
    const unsigned short* __restrict__ w2lo, const float* __restrict__ qv,
    const float* __restrict__ w2b, const float* __restrict__ u1,
    const int* __restrict__ mask, float* __restrict__ scores){
  __shared__ unsigned short a_hi[32*512];
  __shared__ unsigned short a_lo[32*512];
  __shared__ float s_q[512], s_w2b[512], s_u1[512];
  __shared__ float s_part[8][32];
  int t = threadIdx.x;
  int row0 = blockIdx.x * 32;       // global row in [0,131072)
  int b = row0 >> 12;               // row0 / 4096
  s_q[t]   = qv[b*512 + t];
  s_w2b[t] = w2b[t];
  s_u1[t]  = u1[t];
  { // stage doc tile, f32 -> bf16 hi/lo, swizzle 16B-chunk index with row&7
    int r = t >> 4;
    int c0 = (t & 15) * 32;
    const float* src = doc + ((long)(row0 + r) << 9) + c0;
    #pragma unroll
    for (int c = 0; c < 32; c += 4){
      f32x4 v = *(const f32x4*)(src + c);
      u16x4 hv, lv;
      #pragma unroll
      for (int e = 0; e < 4; ++e){
        unsigned short hb = bf16_rne(v[e]);
        hv[e] = hb;
        lv[e] = bf16_rne(v[e] - bf16_f32(hb));
      }
      int k = c0 + c;
      int idx = r*512 + (((k >> 3) ^ (r & 7)) << 3) + (k & 7);
      *(u16x4*)&a_hi[idx] = hv;
      *(u16x4*)&a_lo[idx] = lv;
    }
  }
  __syncthreads();

  int wave = t >> 6, lane = t & 63;
  int lrow = lane & 15, lk = lane >> 4;
  f32x4 acc[2][4];
  #pragma unroll
  for (int mt = 0; mt < 2; ++mt)
    #pragma unroll
    for (int jj = 0; jj < 4; ++jj)
      acc[mt][jj] = (f32x4){0.f, 0.f, 0.f, 0.f};

  #pragma unroll 2
  for (int kt = 0; kt < 16; ++kt){
    short8 ah[2], al[2];
    #pragma unroll
    for (int mt = 0; mt < 2; ++mt){
      int r = mt*16 + lrow;
      int idx = r*512 + ((((kt*4) + lk) ^ (r & 7)) << 3);
      ah[mt] = *(const short8*)&a_hi[idx];
      al[mt] = *(const short8*)&a_lo[idx];
    }
    short8 bh[4], bl[4];
    #pragma unroll
    for (int jj = 0; jj < 4; ++jj){
      int j = (wave + 8*jj)*16 + lrow;
      int off = j*512 + kt*32 + lk*8;
      bh[jj] = *(const short8*)(w2hi + off);
      bl[jj] = *(const short8*)(w2lo + off);
    }
    #pragma unroll
    for (int mt = 0; mt < 2; ++mt)
      #pragma unroll
      for (int jj = 0; jj < 4; ++jj){
        acc[mt][jj] = __builtin_amdgcn_mfma_f32_16x16x32_bf16(bh[jj], ah[mt], acc[mt][jj], 0, 0, 0);
        acc[mt][jj] = __builtin_amdgcn_mfma_f32_16x16x32_bf16(bl[jj], ah[mt], acc[mt][jj], 0, 0, 0);
        acc[mt][jj] = __builtin_amdgcn_mfma_f32_16x16x32_bf16(bh[jj], al[mt], acc[mt][jj], 0, 0, 0);
      }
  }

  // epilogue: D[j_local][m_local], j_local = lk*4+reg (row), m_local = lrow (col)
  float ps0 = 0.f, ps1 = 0.f;
  #pragma unroll
  for (int jj = 0; jj < 4; ++jj){
    #pragma unroll
    for (int r = 0; r < 4; ++r){
      int j = (wave + 8*jj)*16 + lk*4 + r;
      float qw = s_q[j] + s_w2b[j];
      float u = s_u1[j];
      ps0 += tanhf(acc[0][jj][r] + qw) * u;
      ps1 += tanhf(acc[1][jj][r] + qw) * u;
    }
  }
  ps0 += __shfl_xor(ps0, 16); ps0 += __shfl_xor(ps0, 32);
  ps1 += __shfl_xor(ps1, 16); ps1 += __shfl_xor(ps1, 32);
  if (lane < 16){ s_part[wave][lrow] = ps0; s_part[wave][16 + lrow] = ps1; }
  __syncthreads();
  if (t < 32){
    float s = 0.f;
    #pragma unroll
    for (int w = 0; w < 8; ++w) s += s_part[w][t];
    int gl = row0 + t;
    s = mask[gl] ? s : -INFINITY;
    scores[gl] = s;
  }
}

// ---------------- softmax over L per row b (in place) ----------------
__global__ __launch_bounds__(256) void k_softmax(float* __restrict__ sc){
  __shared__ float red[256];
  int b = blockIdx.x, t = threadIdx.x;
  float v[16]; float m = -INFINITY;
  #pragma unroll
  for (int i = 0; i < 16; ++i){ v[i] = sc[b*4096 + i*256 + t]; m = fmaxf(m, v[i]); }
  red[t] = m; __syncthreads();
  for (int s = 128; s > 0; s >>= 1){ if (t < s) red[t] = fmaxf(red[t], red[t+s]); __syncthreads(); }
  m = red[0]; __syncthreads();
  float sum = 0.f;
  #pragma unroll
  for (int i = 0; i < 16; ++i){ v[i] = expf(v[i] - m); sum += v[i]; }
  red[t] = sum; __syncthreads();
  for (int s = 128; s > 0; s >>= 1){ if (t < s) red[t] += red[t+s]; __syncthreads(); }
  float inv = 1.f / red[0];
  #pragma unroll
  for (int i = 0; i < 16; ++i) sc[b*4096 + i*256 + t] = v[i] * inv;
}

// ---------------- context partials: ctxp[b][ch][h] = sum_{l in chunk} attn*doc ---
#define CCH 64
__global__ __launch_bounds__(256) void k_ctx(
    const float* __restrict__ attn, const float* __restrict__ doc,
    float* __restrict__ ctxp){
  __shared__ float sa[CCH];
  int b = blockIdx.y, ch = blockIdx.x, t = threadIdx.x;
  int l0 = ch * CCH;
  if (t < CCH) sa[t] = attn[b*4096 + l0 + t];
  __syncthreads();
  const float* dp = doc + (((long)b*4096 + l0) << 9) + t*2;
  float ax = 0.f, ay = 0.f;
  #pragma unroll 4
  for (int l = 0; l < CCH; ++l){
    f32x2 d = *(const f32x2*)dp;
    float a = sa[l];
    ax += a * d[0]; ay += a * d[1];
    dp += 512;
  }
  int o = (b*64 + ch)*512 + t*2;
  ctxp[o] = ax; ctxp[o+1] = ay;
}

__global__ __launch_bounds__(256) void k_ctx_reduce(
    const float* __restrict__ ctxp, float* __restrict__ cc){
  int idx = blockIdx.x*256 + threadIdx.x;  // 16384
  int b = idx >> 9, hh = idx & 511;
  float s = 0.f;
  #pragma unroll 8
  for (int ch = 0; ch < 64; ++ch) s += ctxp[(b*64 + ch)*512 + hh];
  cc[b*1024 + 512 + hh] = s;   // second half of combined_context
}

// ---------------- output = cc @ Wout^T + bout ----------------
// WG: 256 thr, 8 v-rows; wave w owns b in [8w,8w+8). Lanes along k (coalesced Wout).
__global__ __launch_bounds__(256) void k_out(
    const float* __restrict__ cc, const float* __restrict__ Wout,
    const float* __restrict__ bout, float* __restrict__ out){
  __shared__ float scc[32*256];
  int t = threadIdx.x, wave = t >> 6, lane = t & 63;
  int v0 = blockIdx.x * 8;
  float acc[8][8];
  #pragma unroll
  for (int v = 0; v < 8; ++v)
    #pragma unroll
    for (int bb = 0; bb < 8; ++bb) acc[v][bb] = 0.f;
  for (int kc = 0; kc < 4; ++kc){
    __syncthreads();
    for (int i = t; i < 2048; i += 256){
      int bb = i >> 6;
      int k = (i & 63) * 4;
      *(f32x4*)&scc[bb*256 + k] = *(const f32x4*)&cc[bb*1024 + kc*256 + k];
    }
    __syncthreads();
    int kl = lane * 4;
    f32x4 wv[8];
    #pragma unroll
    for (int v = 0; v < 8; ++v)
      wv[v] = *(const f32x4*)&Wout[(long)(v0 + v)*1024 + kc*256 + kl];
    #pragma unroll
    for (int bb = 0; bb < 8; ++bb){
      f32x4 c4 = *(const f32x4*)&scc[(wave*8 + bb)*256 + kl];
      #pragma unroll
      for (int v = 0; v < 8; ++v)
        acc[v][bb] += wv[v][0]*c4[0] + wv[v][1]*c4[1] + wv[v][2]*c4[2] + wv[v][3]*c4[3];
    }
  }
  #pragma unroll
  for (int v = 0; v < 8; ++v)
    #pragma unroll
    for (int bb = 0; bb < 8; ++bb){
      float a = acc[v][bb];
      a += __shfl_xor(a, 1);  a += __shfl_xor(a, 2);  a += __shfl_xor(a, 4);
      a += __shfl_xor(a, 8);  a += __shfl_xor(a, 16); a += __shfl_xor(a, 32);
      acc[v][bb] = a;
    }
  #pragma unroll
  for (int v = 0; v < 8; ++v){
    float r = acc[v][0];
    #pragma unroll
    for (int bb = 1; bb < 8; ++bb) r = (lane == bb) ? acc[v][bb] : r;
    if (lane < 8) out[(wave*8 + lane)*V_ + v0 + v] = r + bout[v0 + v];
  }
}

extern "C" void kernel_launch(void* const* d_in, const int* in_sizes, int n_in,
                              void* d_out, int out_size, void* d_ws, size_t ws_size,
                              hipStream_t stream){
  const float* x    = (const float*)d_in[0];
  const float* h0   = (const float*)d_in[1];
  const float* c0   = (const float*)d_in[2];
  const float* doc  = (const float*)d_in[3];
  const int*   mask = (const int*)d_in[4];
  const float* Wih  = (const float*)d_in[5];
  const float* Whh  = (const float*)d_in[6];
  const float* bih  = (const float*)d_in[7];
  const float* bhh  = (const float*)d_in[8];
  const float* W1   = (const float*)d_in[9];
  const float* b1   = (const float*)d_in[10];
  const float* W2   = (const float*)d_in[11];
  const float* b2   = (const float*)d_in[12];
  const float* u1   = (const float*)d_in[13];
  const float* Wo   = (const float*)d_in[14];
  const float* bo   = (const float*)d_in[15];
  float* out  = (float*)d_out;
  float* outh = out + B_*V_;          // h at offset 1,024,000
  float* outc = outh + B_*H_;         // c at offset 1,040,384

  float* ws    = (float*)d_ws;
  float* gates = ws;                  // 65536 f32
  float* q     = gates + 65536;       // 16384
  float* cc    = q + 16384;           // 32768 (h | ctx)
  float* attn  = cc + 32768;          // 131072 (scores -> attn in place)
  float* ctxp  = attn + 131072;       // 32*64*512 = 1048576
  unsigned short* w2hi = (unsigned short*)(ctxp + 1048576); // 262144 u16
  unsigned short* w2lo = w2hi + 262144;                      // 262144 u16

  hipLaunchKernelGGL(k_convert_w2, dim3(256), dim3(256), 0, stream, W2, w2hi, w2lo);
  hipLaunchKernelGGL(k_gates, dim3(8, 32), dim3(256), 0, stream, x, h0, Wih, Whh, bih, bhh, gates);
  hipLaunchKernelGGL(k_lstm, dim3(64), dim3(256), 0, stream, gates, c0, outh, outc, cc);
  hipLaunchKernelGGL(k_q, dim3(2, 32), dim3(256), 0, stream, cc, W1, b1, q);
  hipLaunchKernelGGL(k_scores, dim3(4096), dim3(512), 0, stream, doc, w2hi, w2lo, q, b2, u1, mask, attn);
  hipLaunchKernelGGL(k_softmax, dim3(32), dim3(256), 0, stream, attn);
  hipLaunchKernelGGL(k_ctx, dim3(64, 32), dim3(256), 0, stream, attn, doc, ctxp);
  hipLaunchKernelGGL(k_ctx_reduce, dim3(64), dim3(256), 0, stream, ctxp, cc);
  hipLaunchKernelGGL(k_out, dim3(4000), dim3(256), 0, stream, cc, Wo, bo, out);
}

// Round 2
// 435.853 us; speedup vs baseline: 1.6808x; 1.6808x over previous
//
#include <hip/hip_runtime.h>
#include <math.h>

#define B_  32
#define L_  4096
#define H_  512
#define V_  32000
#define MBLK 128

typedef __attribute__((ext_vector_type(4))) float f32x4;
typedef __attribute__((ext_vector_type(2))) float f32x2;
typedef __attribute__((ext_vector_type(8))) short short8;
typedef __attribute__((ext_vector_type(4))) unsigned short u16x4;

__device__ __forceinline__ unsigned short bf16_rne(float x){
  union { float f; unsigned int u; } v; v.f = x;
  unsigned int u = v.u;
  return (unsigned short)((u + 0x7FFFu + ((u >> 16) & 1u)) >> 16);
}
__device__ __forceinline__ float bf16_f32(unsigned short h){
  union { unsigned int u; float f; } v; v.u = ((unsigned int)h) << 16;
  return v.f;
}
// fast tanh: exp2-hw based, ~1e-7 abs err, monotone, saturates safely
__device__ __forceinline__ float tanh_fast(float x){
  float ax = fminf(fabsf(x), 9.0f);
  float e2 = __expf(ax + ax);
  float r = 1.0f - 2.0f * __builtin_amdgcn_rcpf(e2 + 1.0f);
  return __builtin_copysignf(r, x);
}

// ---------------- W2 -> bf16 hi/lo split (1 MB, per call) ----------------
__global__ __launch_bounds__(256) void k_convert_w2(
    const float* __restrict__ w2, unsigned short* __restrict__ hi,
    unsigned short* __restrict__ lo){
  int i = (blockIdx.x * 256 + threadIdx.x) * 4;
  f32x4 v = *(const f32x4*)(w2 + i);
  u16x4 h, l;
  #pragma unroll
  for (int e = 0; e < 4; ++e) {
    unsigned short hb = bf16_rne(v[e]);
    h[e] = hb;
    l[e] = bf16_rne(v[e] - bf16_f32(hb));
  }
  *(u16x4*)(hi + i) = h;
  *(u16x4*)(lo + i) = l;
}

// ---------------- gates = x@Wih^T + b_ih + h0@Whh^T + b_hh ----------------
__global__ __launch_bounds__(256) void k_gates(
    const float* __restrict__ x, const float* __restrict__ h0,
    const float* __restrict__ Wih, const float* __restrict__ Whh,
    const float* __restrict__ bih, const float* __restrict__ bhh,
    float* __restrict__ gates){
  __shared__ float sx[H_], sh[H_];
  int b = blockIdx.y, t = threadIdx.x;
  sx[t] = x[b*H_ + t]; sx[t+256] = x[b*H_ + t + 256];
  sh[t] = h0[b*H_ + t]; sh[t+256] = h0[b*H_ + t + 256];
  __syncthreads();
  int j = blockIdx.x * 256 + t;
  const float* wi = Wih + j*H_;
  const float* wh = Whh + j*H_;
  float acc = bih[j] + bhh[j];
  #pragma unroll 4
  for (int k = 0; k < H_; k += 4) {
    f32x4 a = *(const f32x4*)(wi + k);
    f32x4 c = *(const f32x4*)(wh + k);
    acc += a[0]*sx[k] + a[1]*sx[k+1] + a[2]*sx[k+2] + a[3]*sx[k+3];
    acc += c[0]*sh[k] + c[1]*sh[k+1] + c[2]*sh[k+2] + c[3]*sh[k+3];
  }
  gates[b*2048 + j] = acc;
}

// ---------------- LSTM cell elementwise (exact tanh: h,c are outputs) ------
__global__ __launch_bounds__(256) void k_lstm(
    const float* __restrict__ gates, const float* __restrict__ c0,
    float* __restrict__ out_h, float* __restrict__ out_c, float* __restrict__ cc){
  int idx = blockIdx.x * 256 + threadIdx.x;   // 16384
  int b = idx >> 9, hh = idx & 511;
  const float* g = gates + b*2048;
  float gi = g[hh], gf = g[512+hh], gg = g[1024+hh], go = g[1536+hh];
  float si = 1.f/(1.f+expf(-gi));
  float sf = 1.f/(1.f+expf(-gf));
  float so = 1.f/(1.f+expf(-go));
  float c = sf * c0[idx] + si * tanhf(gg);
  float h = so * tanhf(c);
  out_h[idx] = h; out_c[idx] = c;
  cc[b*1024 + hh] = h;
}

// ---------------- q = h@W1^T + b1 ----------------
__global__ __launch_bounds__(256) void k_q(
    const float* __restrict__ cc, const float* __restrict__ W1,
    const float* __restrict__ b1, float* __restrict__ q){
  __shared__ float shh[H_];
  int b = blockIdx.y, t = threadIdx.x;
  shh[t] = cc[b*1024 + t]; shh[t+256] = cc[b*1024 + t + 256];
  __syncthreads();
  int j = blockIdx.x*256 + t;
  const float* w = W1 + j*H_;
  float acc = b1[j];
  #pragma unroll 4
  for (int k = 0; k < H_; k += 4){
    f32x4 a = *(const f32x4*)(w + k);
    acc += a[0]*shh[k] + a[1]*shh[k+1] + a[2]*shh[k+2] + a[3]*shh[k+3];
  }
  q[b*H_ + j] = acc;
}

// ---------------- scores: 128-row tile, full N=512, BK=64 dbuf pipeline ----
// 8 waves, wave owns j-slice [wave*64, wave*64+64), all 128 rows.
// LDS A layout k-major: [kchunk(8)][row(128)][8 elems] per buffer.
// 3-term split-bf16: Bh*Ah + Bl*Ah + Bh*Al. D[j_local][m_local] mapping
// validated in R1 (j_local = lk*4+reg, m_local = lrow).
__global__ __launch_bounds__(512, 2) void k_scores(
    const float* __restrict__ doc, const unsigned short* __restrict__ w2hi,
    const unsigned short* __restrict__ w2lo, const float* __restrict__ qv,
    const float* __restrict__ w2b, const float* __restrict__ u1,
    const int* __restrict__ mask, float* __restrict__ scores){
  __shared__ short Ah[2][8][MBLK][8];
  __shared__ short Al[2][8][MBLK][8];
  __shared__ float s_qb[512], s_u1[512];
  __shared__ float s_part[8][MBLK];
  int t = threadIdx.x;
  int row0 = blockIdx.x * MBLK;
  int b = row0 >> 12;
  s_qb[t] = qv[b*512 + t] + w2b[t];
  s_u1[t] = u1[t];

  // staging mapping: 4 threads per row, 16 consecutive floats each
  int sr = t >> 2;
  int sc = (t & 3) * 16;
  const float* dbase = doc + (((long)(row0 + sr)) << 9) + sc;
  int kc0 = sc >> 3;   // first of 2 LDS kchunks this thread fills

  int wave = t >> 6, lane = t & 63;
  int lrow = lane & 15, lk = lane >> 4;
  int jbase = wave * 64;

  f32x4 acc[8][4];
  #pragma unroll
  for (int mt = 0; mt < 8; ++mt)
    #pragma unroll
    for (int jj = 0; jj < 4; ++jj)
      acc[mt][jj] = (f32x4){0.f, 0.f, 0.f, 0.f};

  // ---- stage K-step 0 synchronously ----
  {
    f32x4 v[4];
    #pragma unroll
    for (int i = 0; i < 4; ++i) v[i] = *(const f32x4*)(dbase + i*4);
    #pragma unroll
    for (int half = 0; half < 2; ++half){
      short8 hv, lv;
      #pragma unroll
      for (int e = 0; e < 4; ++e){
        union { float f; unsigned u; } ua; ua.f = v[2*half][e];
        unsigned short hb = (unsigned short)(ua.u >> 16);
        hv[e] = (short)hb;
        lv[e] = (short)bf16_rne(v[2*half][e] - bf16_f32(hb));
        union { float f; unsigned u; } ub; ub.f = v[2*half+1][e];
        unsigned short hb2 = (unsigned short)(ub.u >> 16);
        hv[e+4] = (short)hb2;
        lv[e+4] = (short)bf16_rne(v[2*half+1][e] - bf16_f32(hb2));
      }
      *(short8*)&Ah[0][kc0 + half][sr][0] = hv;
      *(short8*)&Al[0][kc0 + half][sr][0] = lv;
    }
  }
  __syncthreads();

  int buf = 0;
  for (int s = 0; s < 8; ++s){
    // issue next-tile global loads early (hide HBM under MFMA)
    f32x4 pf[4];
    if (s < 7){
      const float* p = dbase + (s+1)*64;
      #pragma unroll
      for (int i = 0; i < 4; ++i) pf[i] = *(const f32x4*)(p + i*4);
    }
    #pragma unroll
    for (int ktl = 0; ktl < 2; ++ktl){
      short8 bh[4], bl[4];
      #pragma unroll
      for (int jj = 0; jj < 4; ++jj){
        int off = (jbase + jj*16 + lrow)*512 + s*64 + ktl*32 + lk*8;
        bh[jj] = *(const short8*)(w2hi + off);
        bl[jj] = *(const short8*)(w2lo + off);
      }
      #pragma unroll
      for (int mt = 0; mt < 8; ++mt){
        short8 ah = *(const short8*)&Ah[buf][ktl*4 + lk][mt*16 + lrow][0];
        short8 al = *(const short8*)&Al[buf][ktl*4 + lk][mt*16 + lrow][0];
        #pragma unroll
        for (int jj = 0; jj < 4; ++jj){
          acc[mt][jj] = __builtin_amdgcn_mfma_f32_16x16x32_bf16(bh[jj], ah, acc[mt][jj], 0, 0, 0);
          acc[mt][jj] = __builtin_amdgcn_mfma_f32_16x16x32_bf16(bl[jj], ah, acc[mt][jj], 0, 0, 0);
          acc[mt][jj] = __builtin_amdgcn_mfma_f32_16x16x32_bf16(bh[jj], al, acc[mt][jj], 0, 0, 0);
        }
      }
    }
    if (s < 7){
      #pragma unroll
      for (int half = 0; half < 2; ++half){
        short8 hv, lv;
        #pragma unroll
        for (int e = 0; e < 4; ++e){
          union { float f; unsigned u; } ua; ua.f = pf[2*half][e];
          unsigned short hb = (unsigned short)(ua.u >> 16);
          hv[e] = (short)hb;
          lv[e] = (short)bf16_rne(pf[2*half][e] - bf16_f32(hb));
          union { float f; unsigned u; } ub; ub.f = pf[2*half+1][e];
          unsigned short hb2 = (unsigned short)(ub.u >> 16);
          hv[e+4] = (short)hb2;
          lv[e+4] = (short)bf16_rne(pf[2*half+1][e] - bf16_f32(hb2));
        }
        *(short8*)&Ah[buf^1][kc0 + half][sr][0] = hv;
        *(short8*)&Al[buf^1][kc0 + half][sr][0] = lv;
      }
    }
    __syncthreads();
    buf ^= 1;
  }

  // ---- epilogue: tanh + u1-dot, reduce over j ----
  #pragma unroll
  for (int mt = 0; mt < 8; ++mt){
    float p = 0.f;
    #pragma unroll
    for (int jj = 0; jj < 4; ++jj){
      #pragma unroll
      for (int r = 0; r < 4; ++r){
        int wj = jbase + jj*16 + lk*4 + r;
        p += tanh_fast(acc[mt][jj][r] + s_qb[wj]) * s_u1[wj];
      }
    }
    p += __shfl_xor(p, 16);
    p += __shfl_xor(p, 32);
    if (lane < 16) s_part[wave][mt*16 + lrow] = p;
  }
  __syncthreads();
  if (t < MBLK){
    float sum = 0.f;
    #pragma unroll
    for (int w = 0; w < 8; ++w) sum += s_part[w][t];
    int gl = row0 + t;
    scores[gl] = mask[gl] ? sum : -INFINITY;
  }
}

// ---------------- softmax over L per row b (in place) ----------------
__global__ __launch_bounds__(256) void k_softmax(float* __restrict__ sc){
  __shared__ float red[256];
  int b = blockIdx.x, t = threadIdx.x;
  float v[16]; float m = -INFINITY;
  #pragma unroll
  for (int i = 0; i < 16; ++i){ v[i] = sc[b*4096 + i*256 + t]; m = fmaxf(m, v[i]); }
  red[t] = m; __syncthreads();
  for (int s = 128; s > 0; s >>= 1){ if (t < s) red[t] = fmaxf(red[t], red[t+s]); __syncthreads(); }
  m = red[0]; __syncthreads();
  float sum = 0.f;
  #pragma unroll
  for (int i = 0; i < 16; ++i){ v[i] = expf(v[i] - m); sum += v[i]; }
  red[t] = sum; __syncthreads();
  for (int s = 128; s > 0; s >>= 1){ if (t < s) red[t] += red[t+s]; __syncthreads(); }
  float inv = 1.f / red[0];
  #pragma unroll
  for (int i = 0; i < 16; ++i) sc[b*4096 + i*256 + t] = v[i] * inv;
}

// ---------------- context partials ----------------
#define CCH 64
__global__ __launch_bounds__(256) void k_ctx(
    const float* __restrict__ attn, const float* __restrict__ doc,
    float* __restrict__ ctxp){
  __shared__ float sa[CCH];
  int b = blockIdx.y, ch = blockIdx.x, t = threadIdx.x;
  int l0 = ch * CCH;
  if (t < CCH) sa[t] = attn[b*4096 + l0 + t];
  __syncthreads();
  const float* dp = doc + (((long)b*4096 + l0) << 9) + t*2;
  float ax = 0.f, ay = 0.f;
  #pragma unroll 4
  for (int l = 0; l < CCH; ++l){
    f32x2 d = *(const f32x2*)dp;
    float a = sa[l];
    ax += a * d[0]; ay += a * d[1];
    dp += 512;
  }
  int o = (b*64 + ch)*512 + t*2;
  ctxp[o] = ax; ctxp[o+1] = ay;
}

__global__ __launch_bounds__(256) void k_ctx_reduce(
    const float* __restrict__ ctxp, float* __restrict__ cc){
  int idx = blockIdx.x*256 + threadIdx.x;  // 16384
  int b = idx >> 9, hh = idx & 511;
  float s = 0.f;
  #pragma unroll 8
  for (int ch = 0; ch < 64; ++ch) s += ctxp[(b*64 + ch)*512 + hh];
  cc[b*1024 + 512 + hh] = s;
}

// ---------------- output = cc @ Wout^T + bout ----------------
__global__ __launch_bounds__(256) void k_out(
    const float* __restrict__ cc, const float* __restrict__ Wout,
    const float* __restrict__ bout, float* __restrict__ out){
  __shared__ float scc[32*256];
  int t = threadIdx.x, wave = t >> 6, lane = t & 63;
  int v0 = blockIdx.x * 8;
  float acc[8][8];
  #pragma unroll
  for (int v = 0; v < 8; ++v)
    #pragma unroll
    for (int bb = 0; bb < 8; ++bb) acc[v][bb] = 0.f;
  for (int kc = 0; kc < 4; ++kc){
    __syncthreads();
    for (int i = t; i < 2048; i += 256){
      int bb = i >> 6;
      int k = (i & 63) * 4;
      *(f32x4*)&scc[bb*256 + k] = *(const f32x4*)&cc[bb*1024 + kc*256 + k];
    }
    __syncthreads();
    int kl = lane * 4;
    f32x4 wv[8];
    #pragma unroll
    for (int v = 0; v < 8; ++v)
      wv[v] = *(const f32x4*)&Wout[(long)(v0 + v)*1024 + kc*256 + kl];
    #pragma unroll
    for (int bb = 0; bb < 8; ++bb){
      f32x4 c4 = *(const f32x4*)&scc[(wave*8 + bb)*256 + kl];
      #pragma unroll
      for (int v = 0; v < 8; ++v)
        acc[v][bb] += wv[v][0]*c4[0] + wv[v][1]*c4[1] + wv[v][2]*c4[2] + wv[v][3]*c4[3];
    }
  }
  #pragma unroll
  for (int v = 0; v < 8; ++v)
    #pragma unroll
    for (int bb = 0; bb < 8; ++bb){
      float a = acc[v][bb];
      a += __shfl_xor(a, 1);  a += __shfl_xor(a, 2);  a += __shfl_xor(a, 4);
      a += __shfl_xor(a, 8);  a += __shfl_xor(a, 16); a += __shfl_xor(a, 32);
      acc[v][bb] = a;
    }
  #pragma unroll
  for (int v = 0; v < 8; ++v){
    float r = acc[v][0];
    #pragma unroll
    for (int bb = 1; bb < 8; ++bb) r = (lane == bb) ? acc[v][bb] : r;
    if (lane < 8) out[(wave*8 + lane)*V_ + v0 + v] = r + bout[v0 + v];
  }
}

extern "C" void kernel_launch(void* const* d_in, const int* in_sizes, int n_in,
                              void* d_out, int out_size, void* d_ws, size_t ws_size,
                              hipStream_t stream){
  const float* x    = (const float*)d_in[0];
  const float* h0   = (const float*)d_in[1];
  const float* c0   = (const float*)d_in[2];
  const float* doc  = (const float*)d_in[3];
  const int*   mask = (const int*)d_in[4];
  const float* Wih  = (const float*)d_in[5];
  const float* Whh  = (const float*)d_in[6];
  const float* bih  = (const float*)d_in[7];
  const float* bhh  = (const float*)d_in[8];
  const float* W1   = (const float*)d_in[9];
  const float* b1   = (const float*)d_in[10];
  const float* W2   = (const float*)d_in[11];
  const float* b2   = (const float*)d_in[12];
  const float* u1   = (const float*)d_in[13];
  const float* Wo   = (const float*)d_in[14];
  const float* bo   = (const float*)d_in[15];
  float* out  = (float*)d_out;
  float* outh = out + B_*V_;
  float* outc = outh + B_*H_;

  float* ws    = (float*)d_ws;
  float* gates = ws;                  // 65536 f32
  float* q     = gates + 65536;       // 16384
  float* cc    = q + 16384;           // 32768
  float* attn  = cc + 32768;          // 131072
  float* ctxp  = attn + 131072;       // 1048576
  unsigned short* w2hi = (unsigned short*)(ctxp + 1048576); // 262144 u16
  unsigned short* w2lo = w2hi + 262144;

  hipLaunchKernelGGL(k_convert_w2, dim3(256), dim3(256), 0, stream, W2, w2hi, w2lo);
  hipLaunchKernelGGL(k_gates, dim3(8, 32), dim3(256), 0, stream, x, h0, Wih, Whh, bih, bhh, gates);
  hipLaunchKernelGGL(k_lstm, dim3(64), dim3(256), 0, stream, gates, c0, outh, outc, cc);
  hipLaunchKernelGGL(k_q, dim3(2, 32), dim3(256), 0, stream, cc, W1, b1, q);
  hipLaunchKernelGGL(k_scores, dim3(1024), dim3(512), 0, stream, doc, w2hi, w2lo, q, b2, u1, mask, attn);
  hipLaunchKernelGGL(k_softmax, dim3(32), dim3(256), 0, stream, attn);
  hipLaunchKernelGGL(k_ctx, dim3(64, 32), dim3(256), 0, stream, attn, doc, ctxp);
  hipLaunchKernelGGL(k_ctx_reduce, dim3(64), dim3(256), 0, stream, ctxp, cc);
  hipLaunchKernelGGL(k_out, dim3(4000), dim3(256), 0, stream, cc, Wo, bo, out);
}